// Round 4
// baseline (14185.759 us; speedup 1.0000x reference)
//
#include <hip/hip_runtime.h>
#include <math.h>

#define BB 256
#define TT 128
#define DD 128
#define HH 1024
#define G4 4096
#define TOUT 127
#define OSZ (BB * TOUT * DD)
#define NKB 36                  // (128+1024)/32 K-blocks of the gates GEMM
#define ACTE (16 * NKB * 512)   // u16 elems of one activation frag-blob: 294912

typedef __bf16 bf16x8 __attribute__((ext_vector_type(8)));
typedef float f32x4 __attribute__((ext_vector_type(4)));
typedef unsigned short u16;
typedef unsigned int u32;

__device__ inline u16 f2bf(float f) {
    union { float f; u32 u; } v; v.f = f;
    u32 r = v.u + 0x7FFFu + ((v.u >> 16) & 1u);
    return (u16)(r >> 16);
}
__device__ inline float fsig(float x)  { return __fdividef(1.0f, 1.0f + __expf(-x)); }
__device__ inline float ftanh(float x) { return __fdividef(2.0f, 1.0f + __expf(-2.0f * x)) - 1.0f; }

// Grid barrier: 256 blocks, 32 padded counters (8 arrivals each).
// Relaxed polls + one release fence (arrival) / one acquire fence (exit).
__device__ __forceinline__ void gbar(u32* bars, u32 gen) {
    __syncthreads();
    if (threadIdx.x == 0) {
        __builtin_amdgcn_fence(__ATOMIC_RELEASE, "agent");
        __hip_atomic_fetch_add(&bars[(blockIdx.x & 31) << 4], 1u,
                               __ATOMIC_RELAXED, __HIP_MEMORY_SCOPE_AGENT);
    }
    if (threadIdx.x < 32) {
        while (__hip_atomic_load(&bars[threadIdx.x << 4],
                                 __ATOMIC_RELAXED, __HIP_MEMORY_SCOPE_AGENT) < gen * 8u)
            __builtin_amdgcn_s_sleep(4);
    }
    __builtin_amdgcn_fence(__ATOMIC_ACQUIRE, "agent");
    __syncthreads();
}

struct SArgs {
    u16 *acts, *actp;                       // 2 x ACTE each (double-buffered blobs)
    const u16 *wS, *wP, *fswb, *pfcb;       // frag-ordered weight blobs
    const float *bS, *bP, *fsb, *pfb, *x;
    float* out;
    u32* bars;
};

// Gates GEMM 256x4096, K=1152 + fused LSTM cell epilogue. 64m x 64n per block,
// 8 waves = kg(2, K-split) x wm(2) x wn(2); register-direct frag loads, no
// barriers in K-loop; 2-way LDS reduce; epilogue on kg==0 waves. c in LDS.
__device__ __forceinline__ void lstm_phase(
    const u16* __restrict__ act, const u16* __restrict__ wb,
    const float* __restrict__ bias, float* __restrict__ cst /*LDS [64][16]*/,
    u16* __restrict__ hact, float* red /*LDS 16KB*/,
    int bid, int w, int lane)
{
    const int wn = w & 1, wm = (w >> 1) & 1, kg = w >> 2;
    const int mb = ((bid >> 6) << 2) + wm * 2;
    const int nb = ((bid & 63) << 2) + wn * 2;

    const u16* a0 = act + (((size_t)(mb + 0) * NKB + kg * 18) * 64 + lane) * 8;
    const u16* a1 = act + (((size_t)(mb + 1) * NKB + kg * 18) * 64 + lane) * 8;
    const u16* b0 = wb  + (((size_t)(nb + 0) * NKB + kg * 18) * 64 + lane) * 8;
    const u16* b1 = wb  + (((size_t)(nb + 1) * NKB + kg * 18) * 64 + lane) * 8;

    f32x4 acc[2][2] = {};
#pragma unroll 6
    for (int it = 0; it < 18; ++it) {
        bf16x8 av0 = *(const bf16x8*)(a0 + it * 512);
        bf16x8 av1 = *(const bf16x8*)(a1 + it * 512);
        bf16x8 bv0 = *(const bf16x8*)(b0 + it * 512);
        bf16x8 bv1 = *(const bf16x8*)(b1 + it * 512);
        acc[0][0] = __builtin_amdgcn_mfma_f32_16x16x32_bf16(av0, bv0, acc[0][0], 0, 0, 0);
        acc[0][1] = __builtin_amdgcn_mfma_f32_16x16x32_bf16(av0, bv1, acc[0][1], 0, 0, 0);
        acc[1][0] = __builtin_amdgcn_mfma_f32_16x16x32_bf16(av1, bv0, acc[1][0], 0, 0, 0);
        acc[1][1] = __builtin_amdgcn_mfma_f32_16x16x32_bf16(av1, bv1, acc[1][1], 0, 0, 0);
    }

    if (kg == 1) {
#pragma unroll
        for (int mi = 0; mi < 2; ++mi)
#pragma unroll
        for (int ni = 0; ni < 2; ++ni)
            *(f32x4*)&red[(((((wm << 1) | wn) << 1 | mi) << 1 | ni) << 8) + (lane << 2)] = acc[mi][ni];
    }
    __syncthreads();

    if (kg == 0) {
        const int col = lane & 15, row4 = (lane >> 4) << 2, g0 = lane & 3;
        const int m_base = ((bid >> 6) << 6) + wm * 32;
        const int n_base = ((bid & 63) << 6) + wn * 32;
#pragma unroll
        for (int mi = 0; mi < 2; ++mi)
#pragma unroll
        for (int ni = 0; ni < 2; ++ni) {
            f32x4 s1 = *(const f32x4*)&red[(((((wm << 1) | wn) << 1 | mi) << 1 | ni) << 8) + (lane << 2)];
            const int n = n_base + ni * 16 + col;
            const float bv = bias[n];
#pragma unroll
            for (int rr = 0; rr < 4; ++rr) {
                float v = acc[mi][ni][rr] + s1[rr] + bv;
                float v1 = __shfl_xor(v, 1);
                float v2 = __shfl_xor(v, 2);
                float v3 = __shfl_xor(v, 3);
                if (g0 == 0) {  // lane holds gate i; v1=f, v2=g, v3=o
                    const int m = m_base + mi * 16 + row4 + rr;
                    const int j = n >> 2;
                    const int ml = wm * 32 + mi * 16 + row4 + rr;
                    const int jl = (wn * 32 + ni * 16 + col) >> 2;
                    float cp = cst[ml * 16 + jl];
                    float cy = cp * fsig(v1) + fsig(v) * ftanh(v2);
                    float hy = fsig(v3) * ftanh(cy);
                    cst[ml * 16 + jl] = cy;
                    hact[(((size_t)(m >> 4) * NKB + (4 + (j >> 5))) * 64 +
                          ((m & 15) + (((j >> 3) & 3) << 4))) * 8 + (j & 7)] = f2bf(hy);
                }
            }
        }
    }
}

__global__ __launch_bounds__(512, 2) void k_scan(SArgs A)
{
    __shared__ __align__(16) float red[4096];   // 16 KB reduce scratch
    __shared__ float cst[2][64][16];            // 8 KB persistent c state (s,p)

    const int bid = blockIdx.x, tid = threadIdx.x;
    const int w = tid >> 6, lane = tid & 63;

    for (int i = tid; i < 2 * 64 * 16; i += 512) ((float*)cst)[i] = 0.f;

    float* o_mask = A.out;
    float* o_x0   = A.out + 1 * (size_t)OSZ;
    float* o_x1   = A.out + 2 * (size_t)OSZ;
    float* o_reg  = A.out + 3 * (size_t)OSZ;
    float* o_mu   = A.out + 4 * (size_t)OSZ;
    float* o_prob = A.out + 5 * (size_t)OSZ;
    float* o_z    = A.out + 6 * (size_t)OSZ;

    u32 gen = 0;

    for (int t = 0; t < TOUT; ++t) {
        const u16* s_cur = A.acts + (size_t)(t & 1) * ACTE;
        u16*       s_nxt = A.acts + (size_t)((t + 1) & 1) * ACTE;
        u16*       p_cur = A.actp + (size_t)(t & 1) * ACTE;
        u16*       p_nxt = A.actp + (size_t)((t + 1) & 1) * ACTE;

        // ---- phase S ----
        lstm_phase(s_cur, A.wS, A.bS, &cst[0][0][0], s_nxt, red, bid, w, lane);
        gbar(A.bars, ++gen);

        // ---- phase M: mu GEMM (256x128,K=1024), 128 blocks, 8-wave K-split ----
        if (bid < 128) {
            const int bm = bid >> 3, bn = bid & 7;
            f32x4 acc = {};
#pragma unroll
            for (int i = 0; i < 4; ++i) {
                const int kb = (w << 2) + i;
                bf16x8 av = *(const bf16x8*)(s_nxt + (((size_t)bm * NKB + 4 + kb) * 64 + lane) * 8);
                bf16x8 bv = *(const bf16x8*)(A.fswb + (((size_t)bn * 32 + kb) * 64 + lane) * 8);
                acc = __builtin_amdgcn_mfma_f32_16x16x32_bf16(av, bv, acc, 0, 0, 0);
            }
            *(f32x4*)&red[(w * 64 + lane) << 2] = acc;
            __syncthreads();
            if (tid < 256) {
                const int m16 = tid >> 4, d16 = tid & 15;
                const int rl = ((m16 >> 2) << 4) | d16, rr = m16 & 3;
                float v = 0.f;
#pragma unroll
                for (int ww = 0; ww < 8; ++ww) v += red[((ww * 64 + rl) << 2) + rr];
                const int m = (bm << 4) + m16, d = (bn << 4) + d16;
                float mu = v + A.fsb[d];
                float mask = fminf(fmaxf(mu + 0.5f, 0.f), 1.f);
                float reg = 0.5f * (1.0f + erff((mu + 0.5f) * 1.41421356237f));
                const size_t o = (size_t)m * (TOUT * DD) + (size_t)t * DD + d;
                o_mask[o] = mask; o_reg[o] = reg; o_mu[o] = mu; o_prob[o] = reg; o_z[o] = mu;
                float xv = A.x[(size_t)m * (TT * DD) + (size_t)(t + 1) * DD + d];
                p_cur[(((size_t)(m >> 4) * NKB + (d >> 5)) * 64 +
                       ((m & 15) + (((d >> 3) & 3) << 4))) * 8 + (d & 7)] = f2bf(mask * xv);
            }
        }
        gbar(A.bars, ++gen);

        // ---- phase P ----
        lstm_phase(p_cur, A.wP, A.bP, &cst[1][0][0], p_nxt, red, bid, w, lane);
        gbar(A.bars, ++gen);

        // ---- phase F: fc GEMM (256x256,K=1024), 256 blocks, 8-wave K-split ----
        {
            const int bm = bid >> 4, bn = bid & 15;
            f32x4 acc = {};
#pragma unroll
            for (int i = 0; i < 4; ++i) {
                const int kb = (w << 2) + i;
                bf16x8 av = *(const bf16x8*)(p_nxt + (((size_t)bm * NKB + 4 + kb) * 64 + lane) * 8);
                bf16x8 bv = *(const bf16x8*)(A.pfcb + (((size_t)bn * 32 + kb) * 64 + lane) * 8);
                acc = __builtin_amdgcn_mfma_f32_16x16x32_bf16(av, bv, acc, 0, 0, 0);
            }
            *(f32x4*)&red[(w * 64 + lane) << 2] = acc;
            __syncthreads();
            if (tid < 256) {
                const int m16 = tid >> 4, d16 = tid & 15;
                const int rl = ((m16 >> 2) << 4) | d16, rr = m16 & 3;
                float v = 0.f;
#pragma unroll
                for (int ww = 0; ww < 8; ++ww) v += red[((ww * 64 + rl) << 2) + rr];
                const int m = (bm << 4) + m16, n = (bn << 4) + d16;
                v += A.pfb[n];
                const size_t ob = (size_t)m * (TOUT * DD) + (size_t)t * DD;
                if (n < DD) {
                    o_x0[ob + n] = v;
                    float mk = o_mask[ob + n];
                    float xv = A.x[(size_t)m * (TT * DD) + (size_t)(t + 1) * DD + n];
                    s_nxt[(((size_t)(m >> 4) * NKB + (n >> 5)) * 64 +
                           ((m & 15) + (((n >> 3) & 3) << 4))) * 8 + (n & 7)] =
                        f2bf(mk * xv + (1.f - mk) * v);
                } else {
                    o_x1[ob + (n - DD)] = v;
                }
            }
        }
        gbar(A.bars, ++gen);
    }
}

// ---------------- setup kernels (once per call) ----------------

__global__ void k_wgates(const float* __restrict__ wx, const float* __restrict__ wh,
                         u16* __restrict__ blob) {
    int i = blockIdx.x * 256 + threadIdx.x;
    if (i >= 256 * NKB * 64) return;
    int lane = i & 63, cblk = (i >> 6) % NKB, rblk = (i >> 6) / NKB;
    int n = (rblk << 4) | (lane & 15);
    int c = (cblk << 5) + ((lane >> 4) << 3);
    int orow = ((n & 3) << 10) | (n >> 2);
    const float* s = (cblk < 4) ? (wx + (size_t)orow * DD + c)
                                : (wh + (size_t)orow * HH + (c - 128));
    u16* d = blob + (size_t)i * 8;
#pragma unroll
    for (int k = 0; k < 8; ++k) d[k] = f2bf(s[k]);
}

__global__ void k_wplain(const float* __restrict__ wsrc, u16* __restrict__ blob,
                         int nblk, int K) {
    int CB = K >> 5;
    int i = blockIdx.x * 256 + threadIdx.x;
    if (i >= nblk * CB * 64) return;
    int lane = i & 63, cblk = (i >> 6) % CB, rblk = (i >> 6) / CB;
    int r = (rblk << 4) | (lane & 15);
    int c = (cblk << 5) + ((lane >> 4) << 3);
    const float* s = wsrc + (size_t)r * K + c;
    u16* d = blob + (size_t)i * 8;
#pragma unroll
    for (int k = 0; k < 8; ++k) d[k] = f2bf(s[k]);
}

__global__ void k_bias2(const float* __restrict__ bx, const float* __restrict__ bh,
                        float* __restrict__ dst) {
    int r = blockIdx.x * 256 + threadIdx.x;
    if (r < G4) {
        int o = ((r & 3) << 10) | (r >> 2);
        dst[r] = bx[o] + bh[o];
    }
}

__global__ void k_zero(u16* acts, u16* actp, u32* bars) {
    size_t i = (size_t)blockIdx.x * 256 + threadIdx.x;
    if (i < 2 * (size_t)ACTE) { acts[i] = 0; actp[i] = 0; }
    if (i < 512) bars[i] = 0;
}

__global__ void k_fillx(const float* __restrict__ x, u16* __restrict__ acts) {
    int i = blockIdx.x * 256 + threadIdx.x;
    if (i >= BB * DD) return;
    int m = i >> 7, d = i & 127;
    acts[(((size_t)(m >> 4) * NKB + (d >> 5)) * 64 +
          ((m & 15) + (((d >> 3) & 3) << 4))) * 8 + (d & 7)] =
        f2bf(x[(size_t)m * (TT * DD) + d]);
}

extern "C" void kernel_launch(void* const* d_in, const int* in_sizes, int n_in,
                              void* d_out, int out_size, void* d_ws, size_t ws_size,
                              hipStream_t stream) {
    const float* x       = (const float*)d_in[0];
    const float* s_x2h_w = (const float*)d_in[1];
    const float* s_x2h_b = (const float*)d_in[2];
    const float* s_h2h_w = (const float*)d_in[3];
    const float* s_h2h_b = (const float*)d_in[4];
    const float* p_x2h_w = (const float*)d_in[5];
    const float* p_x2h_b = (const float*)d_in[6];
    const float* p_h2h_w = (const float*)d_in[7];
    const float* p_h2h_b = (const float*)d_in[8];
    const float* p_fc_w  = (const float*)d_in[9];
    const float* p_fc_b  = (const float*)d_in[10];
    const float* fs_w    = (const float*)d_in[11];
    const float* fs_b    = (const float*)d_in[12];

    char* ws = (char*)d_ws;
    size_t off = 0;
    auto alloc = [&](size_t bytes) { void* p = ws + off; off += (bytes + 255) & ~(size_t)255; return p; };
    u16*   wS   = (u16*)  alloc((size_t)G4 * 1152 * 2);
    u16*   wP   = (u16*)  alloc((size_t)G4 * 1152 * 2);
    u16*   fswb = (u16*)  alloc((size_t)8 * 32 * 512 * 2);
    u16*   pfcb = (u16*)  alloc((size_t)16 * 32 * 512 * 2);
    float* bS   = (float*)alloc((size_t)G4 * 4);
    float* bP   = (float*)alloc((size_t)G4 * 4);
    u16*   acts = (u16*)  alloc((size_t)2 * ACTE * 2);
    u16*   actp = (u16*)  alloc((size_t)2 * ACTE * 2);
    u32*   bars = (u32*)  alloc(2048);

    k_wgates<<<dim3(2304), 256, 0, stream>>>(s_x2h_w, s_h2h_w, wS);
    k_wgates<<<dim3(2304), 256, 0, stream>>>(p_x2h_w, p_h2h_w, wP);
    k_wplain<<<dim3(64),  256, 0, stream>>>(fs_w, fswb, 8, 1024);
    k_wplain<<<dim3(128), 256, 0, stream>>>(p_fc_w, pfcb, 16, 1024);
    k_bias2<<<dim3(16), 256, 0, stream>>>(s_x2h_b, s_h2h_b, bS);
    k_bias2<<<dim3(16), 256, 0, stream>>>(p_x2h_b, p_h2h_b, bP);
    k_zero<<<dim3(2304), 256, 0, stream>>>(acts, actp, bars);
    k_fillx<<<dim3(128), 256, 0, stream>>>(x, acts);

    SArgs sa;
    sa.acts = acts; sa.actp = actp;
    sa.wS = wS; sa.wP = wP; sa.fswb = fswb; sa.pfcb = pfcb;
    sa.bS = bS; sa.bP = bP; sa.fsb = fs_b; sa.pfb = p_fc_b; sa.x = x;
    sa.out = (float*)d_out; sa.bars = bars;

    void* kargs[] = { &sa };
    hipError_t e = hipLaunchCooperativeKernel((const void*)k_scan, dim3(256), dim3(512),
                                              kargs, 0, stream);
    if (e != hipSuccess) {
        k_scan<<<dim3(256), dim3(512), 0, stream>>>(sa);
    }
}

// Round 5
// 5442.496 us; speedup vs baseline: 2.6065x; 2.6065x over previous
//
#include <hip/hip_runtime.h>
#include <math.h>

#define BB 256
#define TT 128
#define DD 128
#define HH 1024
#define G4 4096
#define TOUT 127
#define OSZ (BB * TOUT * DD)
#define NKB 36                  // (128+1024)/32 K-blocks of the gates GEMM
#define ACTE (16 * NKB * 512)   // u16 elems of one activation frag-blob: 294912

typedef __bf16 bf16x8 __attribute__((ext_vector_type(8)));
typedef float f32x4 __attribute__((ext_vector_type(4)));
typedef unsigned short u16;
typedef unsigned int u32;
typedef unsigned long long u64;

__device__ inline u16 f2bf(float f) {
    union { float f; u32 u; } v; v.f = f;
    u32 r = v.u + 0x7FFFu + ((v.u >> 16) & 1u);
    return (u16)(r >> 16);
}
__device__ inline float fsig(float x)  { return __fdividef(1.0f, 1.0f + __expf(-x)); }
__device__ inline float ftanh(float x) { return __fdividef(2.0f, 1.0f + __expf(-2.0f * x)) - 1.0f; }

// Coherent (agent-scope, relaxed) activation access: loads bypass stale L1/L2
// (served from L3 coherence point); stores write through. NO cache fences.
__device__ __forceinline__ bf16x8 ld_act(const u16* p) {
    union { u64 q[2]; bf16x8 v; } u;
    u.q[0] = __hip_atomic_load((u64*)p,     __ATOMIC_RELAXED, __HIP_MEMORY_SCOPE_AGENT);
    u.q[1] = __hip_atomic_load((u64*)p + 1, __ATOMIC_RELAXED, __HIP_MEMORY_SCOPE_AGENT);
    return u.v;
}
__device__ __forceinline__ void st_u32(u16* p, u32 v) {
    __hip_atomic_store((u32*)p, v, __ATOMIC_RELAXED, __HIP_MEMORY_SCOPE_AGENT);
}

// Grid barrier with NO cache-maintenance: every wave drains its outstanding
// (write-through) stores, then one relaxed add per block, relaxed polls.
__device__ __forceinline__ void gbar(u32* bars, u32 gen) {
    asm volatile("s_waitcnt vmcnt(0)" ::: "memory");
    __syncthreads();
    if (threadIdx.x == 0)
        __hip_atomic_fetch_add(&bars[(blockIdx.x & 31) << 4], 1u,
                               __ATOMIC_RELAXED, __HIP_MEMORY_SCOPE_AGENT);
    if (threadIdx.x < 32) {
        while (__hip_atomic_load(&bars[threadIdx.x << 4],
                                 __ATOMIC_RELAXED, __HIP_MEMORY_SCOPE_AGENT) < gen * 8u)
            __builtin_amdgcn_s_sleep(4);
    }
    __syncthreads();
}

struct SArgs {
    u16 *acts, *actp;                       // 2 x ACTE each (double-buffered blobs)
    const u16 *wS, *wP, *fswb, *pfcb;       // frag-ordered weight blobs (L2-resident)
    const float *bS, *bP, *fsb, *pfb, *x;
    float* mbuf;                            // mask scratch (coherent path)
    float* out;
    u32* bars;
};

// Gates GEMM 256x4096, K=1152 + fused LSTM cell epilogue. 64m x 64n per block,
// 8 waves = kg(2, K-split) x wm(2) x wn(2); register-direct loads (act via
// coherent 8B atomics, weights normal); 2-way LDS reduce; epilogue on kg==0.
__device__ __forceinline__ void lstm_phase(
    const u16* __restrict__ act, const u16* __restrict__ wb,
    const float* __restrict__ bias, float* __restrict__ cst /*LDS [64][16]*/,
    u16* __restrict__ hact, float* red /*LDS 16KB*/,
    int bid, int w, int lane)
{
    const int wn = w & 1, wm = (w >> 1) & 1, kg = w >> 2;
    const int mb = ((bid >> 6) << 2) + wm * 2;
    const int nb = ((bid & 63) << 2) + wn * 2;

    const u16* a0 = act + (((size_t)(mb + 0) * NKB + kg * 18) * 64 + lane) * 8;
    const u16* a1 = act + (((size_t)(mb + 1) * NKB + kg * 18) * 64 + lane) * 8;
    const u16* b0 = wb  + (((size_t)(nb + 0) * NKB + kg * 18) * 64 + lane) * 8;
    const u16* b1 = wb  + (((size_t)(nb + 1) * NKB + kg * 18) * 64 + lane) * 8;

    f32x4 acc[2][2] = {};
#pragma unroll 6
    for (int it = 0; it < 18; ++it) {
        bf16x8 av0 = ld_act(a0 + it * 512);
        bf16x8 av1 = ld_act(a1 + it * 512);
        bf16x8 bv0 = *(const bf16x8*)(b0 + it * 512);
        bf16x8 bv1 = *(const bf16x8*)(b1 + it * 512);
        acc[0][0] = __builtin_amdgcn_mfma_f32_16x16x32_bf16(av0, bv0, acc[0][0], 0, 0, 0);
        acc[0][1] = __builtin_amdgcn_mfma_f32_16x16x32_bf16(av0, bv1, acc[0][1], 0, 0, 0);
        acc[1][0] = __builtin_amdgcn_mfma_f32_16x16x32_bf16(av1, bv0, acc[1][0], 0, 0, 0);
        acc[1][1] = __builtin_amdgcn_mfma_f32_16x16x32_bf16(av1, bv1, acc[1][1], 0, 0, 0);
    }

    if (kg == 1) {
#pragma unroll
        for (int mi = 0; mi < 2; ++mi)
#pragma unroll
        for (int ni = 0; ni < 2; ++ni)
            *(f32x4*)&red[(((((wm << 1) | wn) << 1 | mi) << 1 | ni) << 8) + (lane << 2)] = acc[mi][ni];
    }
    __syncthreads();

    if (kg == 0) {
        const int col = lane & 15, row4 = (lane >> 4) << 2, g0 = lane & 3;
        const int m_base = ((bid >> 6) << 6) + wm * 32;
        const int n_base = ((bid & 63) << 6) + wn * 32;
#pragma unroll
        for (int mi = 0; mi < 2; ++mi)
#pragma unroll
        for (int ni = 0; ni < 2; ++ni) {
            f32x4 s1 = *(const f32x4*)&red[(((((wm << 1) | wn) << 1 | mi) << 1 | ni) << 8) + (lane << 2)];
            const int n = n_base + ni * 16 + col;
            const float bv = bias[n];
#pragma unroll
            for (int rr = 0; rr < 4; ++rr) {
                float v = acc[mi][ni][rr] + s1[rr] + bv;
                float v1 = __shfl_xor(v, 1);
                float v2 = __shfl_xor(v, 2);
                float v3 = __shfl_xor(v, 3);
                const int m = m_base + mi * 16 + row4 + rr;
                const int j = n >> 2;
                u32 hbits = 0;
                if (g0 == 0) {  // lane holds gate i; v1=f, v2=g, v3=o
                    const int ml = wm * 32 + mi * 16 + row4 + rr;
                    const int jl = (wn * 32 + ni * 16 + col) >> 2;
                    float cp = cst[ml * 16 + jl];
                    float cy = cp * fsig(v1) + fsig(v) * ftanh(v2);
                    float hy = fsig(v3) * ftanh(cy);
                    cst[ml * 16 + jl] = cy;
                    hbits = (u32)f2bf(hy);
                }
                // pair (j even, j odd) across lanes l and l^4 -> one 4B store
                u32 pv = hbits | (((u32)__shfl_xor((int)hbits, 4)) << 16);
                if ((lane & 7) == 0)
                    st_u32(&hact[(((size_t)(m >> 4) * NKB + (4 + (j >> 5))) * 64 +
                                  ((m & 15) + (((j >> 3) & 3) << 4))) * 8 + (j & 7)], pv);
            }
        }
    }
}

__global__ __launch_bounds__(512, 2) void k_scan(SArgs A)
{
    __shared__ __align__(16) float red[4096];   // 16 KB reduce scratch
    __shared__ float cst[2][64][16];            // 8 KB persistent c state (s,p)

    const int bid = blockIdx.x, tid = threadIdx.x;
    const int w = tid >> 6, lane = tid & 63;

    for (int i = tid; i < 2 * 64 * 16; i += 512) ((float*)cst)[i] = 0.f;

    float* o_mask = A.out;
    float* o_x0   = A.out + 1 * (size_t)OSZ;
    float* o_x1   = A.out + 2 * (size_t)OSZ;
    float* o_reg  = A.out + 3 * (size_t)OSZ;
    float* o_mu   = A.out + 4 * (size_t)OSZ;
    float* o_prob = A.out + 5 * (size_t)OSZ;
    float* o_z    = A.out + 6 * (size_t)OSZ;

    u32 gen = 0;

    for (int t = 0; t < TOUT; ++t) {
        const u16* s_cur = A.acts + (size_t)(t & 1) * ACTE;
        u16*       s_nxt = A.acts + (size_t)((t + 1) & 1) * ACTE;
        u16*       p_cur = A.actp + (size_t)(t & 1) * ACTE;
        u16*       p_nxt = A.actp + (size_t)((t + 1) & 1) * ACTE;

        // ---- phase S ----
        lstm_phase(s_cur, A.wS, A.bS, &cst[0][0][0], s_nxt, red, bid, w, lane);
        gbar(A.bars, ++gen);

        // ---- phase M: mu GEMM (256x128,K=1024), 128 blocks, 8-wave K-split ----
        if (bid < 128) {
            const int bm = bid >> 3, bn = bid & 7;
            f32x4 acc = {};
#pragma unroll
            for (int i = 0; i < 4; ++i) {
                const int kb = (w << 2) + i;
                bf16x8 av = ld_act(s_nxt + (((size_t)bm * NKB + 4 + kb) * 64 + lane) * 8);
                bf16x8 bv = *(const bf16x8*)(A.fswb + (((size_t)bn * 32 + kb) * 64 + lane) * 8);
                acc = __builtin_amdgcn_mfma_f32_16x16x32_bf16(av, bv, acc, 0, 0, 0);
            }
            *(f32x4*)&red[(w * 64 + lane) << 2] = acc;
            __syncthreads();
            if (tid < 256) {
                const int m16 = tid >> 4, d16 = tid & 15;
                const int rl = ((m16 >> 2) << 4) | d16, rr = m16 & 3;
                float v = 0.f;
#pragma unroll
                for (int ww = 0; ww < 8; ++ww) v += red[((ww * 64 + rl) << 2) + rr];
                const int m = (bm << 4) + m16, d = (bn << 4) + d16;
                float mu = v + A.fsb[d];
                float mask = fminf(fmaxf(mu + 0.5f, 0.f), 1.f);
                float reg = 0.5f * (1.0f + erff((mu + 0.5f) * 1.41421356237f));
                const size_t o = (size_t)m * (TOUT * DD) + (size_t)t * DD + d;
                o_mask[o] = mask; o_reg[o] = reg; o_mu[o] = mu; o_prob[o] = reg; o_z[o] = mu;
                __hip_atomic_store(&A.mbuf[m * DD + d], mask,
                                   __ATOMIC_RELAXED, __HIP_MEMORY_SCOPE_AGENT);
                float xv = A.x[(size_t)m * (TT * DD) + (size_t)(t + 1) * DD + d];
                u32 xb = (u32)f2bf(mask * xv);
                u32 pv = xb | (((u32)__shfl_xor((int)xb, 1)) << 16);
                if ((d16 & 1) == 0)
                    st_u32(&p_cur[(((size_t)(m >> 4) * NKB + (d >> 5)) * 64 +
                                   ((m & 15) + (((d >> 3) & 3) << 4))) * 8 + (d & 7)], pv);
            }
        }
        gbar(A.bars, ++gen);

        // ---- phase P ----
        lstm_phase(p_cur, A.wP, A.bP, &cst[1][0][0], p_nxt, red, bid, w, lane);
        gbar(A.bars, ++gen);

        // ---- phase F: fc GEMM (256x256,K=1024), 256 blocks, 8-wave K-split ----
        {
            const int bm = bid >> 4, bn = bid & 15;
            f32x4 acc = {};
#pragma unroll
            for (int i = 0; i < 4; ++i) {
                const int kb = (w << 2) + i;
                bf16x8 av = ld_act(p_nxt + (((size_t)bm * NKB + 4 + kb) * 64 + lane) * 8);
                bf16x8 bv = *(const bf16x8*)(A.pfcb + (((size_t)bn * 32 + kb) * 64 + lane) * 8);
                acc = __builtin_amdgcn_mfma_f32_16x16x32_bf16(av, bv, acc, 0, 0, 0);
            }
            *(f32x4*)&red[(w * 64 + lane) << 2] = acc;
            __syncthreads();
            if (tid < 256) {
                const int m16 = tid >> 4, d16 = tid & 15;
                const int rl = ((m16 >> 2) << 4) | d16, rr = m16 & 3;
                float v = 0.f;
#pragma unroll
                for (int ww = 0; ww < 8; ++ww) v += red[((ww * 64 + rl) << 2) + rr];
                const int m = (bm << 4) + m16, n = (bn << 4) + d16;
                v += A.pfb[n];
                const size_t ob = (size_t)m * (TOUT * DD) + (size_t)t * DD;
                if (bn < 8) {  // n < DD (block-uniform)
                    o_x0[ob + n] = v;
                    float mk = __hip_atomic_load(&A.mbuf[m * DD + n],
                                                 __ATOMIC_RELAXED, __HIP_MEMORY_SCOPE_AGENT);
                    float xv = A.x[(size_t)m * (TT * DD) + (size_t)(t + 1) * DD + n];
                    u32 ib = (u32)f2bf(mk * xv + (1.f - mk) * v);
                    u32 pv = ib | (((u32)__shfl_xor((int)ib, 1)) << 16);
                    if ((d16 & 1) == 0)
                        st_u32(&s_nxt[(((size_t)(m >> 4) * NKB + (n >> 5)) * 64 +
                                       ((m & 15) + (((n >> 3) & 3) << 4))) * 8 + (n & 7)], pv);
                } else {
                    o_x1[ob + (n - DD)] = v;
                }
            }
        }
        gbar(A.bars, ++gen);
    }
}

// ---------------- setup kernels (once per call) ----------------

__global__ void k_wgates(const float* __restrict__ wx, const float* __restrict__ wh,
                         u16* __restrict__ blob) {
    int i = blockIdx.x * 256 + threadIdx.x;
    if (i >= 256 * NKB * 64) return;
    int lane = i & 63, cblk = (i >> 6) % NKB, rblk = (i >> 6) / NKB;
    int n = (rblk << 4) | (lane & 15);
    int c = (cblk << 5) + ((lane >> 4) << 3);
    int orow = ((n & 3) << 10) | (n >> 2);
    const float* s = (cblk < 4) ? (wx + (size_t)orow * DD + c)
                                : (wh + (size_t)orow * HH + (c - 128));
    u16* d = blob + (size_t)i * 8;
#pragma unroll
    for (int k = 0; k < 8; ++k) d[k] = f2bf(s[k]);
}

__global__ void k_wplain(const float* __restrict__ wsrc, u16* __restrict__ blob,
                         int nblk, int K) {
    int CB = K >> 5;
    int i = blockIdx.x * 256 + threadIdx.x;
    if (i >= nblk * CB * 64) return;
    int lane = i & 63, cblk = (i >> 6) % CB, rblk = (i >> 6) / CB;
    int r = (rblk << 4) | (lane & 15);
    int c = (cblk << 5) + ((lane >> 4) << 3);
    const float* s = wsrc + (size_t)r * K + c;
    u16* d = blob + (size_t)i * 8;
#pragma unroll
    for (int k = 0; k < 8; ++k) d[k] = f2bf(s[k]);
}

__global__ void k_bias2(const float* __restrict__ bx, const float* __restrict__ bh,
                        float* __restrict__ dst) {
    int r = blockIdx.x * 256 + threadIdx.x;
    if (r < G4) {
        int o = ((r & 3) << 10) | (r >> 2);
        dst[r] = bx[o] + bh[o];
    }
}

__global__ void k_zero(u16* acts, u16* actp, u32* bars) {
    size_t i = (size_t)blockIdx.x * 256 + threadIdx.x;
    if (i < 2 * (size_t)ACTE) { acts[i] = 0; actp[i] = 0; }
    if (i < 512) bars[i] = 0;
}

__global__ void k_fillx(const float* __restrict__ x, u16* __restrict__ acts) {
    int i = blockIdx.x * 256 + threadIdx.x;
    if (i >= BB * DD) return;
    int m = i >> 7, d = i & 127;
    acts[(((size_t)(m >> 4) * NKB + (d >> 5)) * 64 +
          ((m & 15) + (((d >> 3) & 3) << 4))) * 8 + (d & 7)] =
        f2bf(x[(size_t)m * (TT * DD) + d]);
}

extern "C" void kernel_launch(void* const* d_in, const int* in_sizes, int n_in,
                              void* d_out, int out_size, void* d_ws, size_t ws_size,
                              hipStream_t stream) {
    const float* x       = (const float*)d_in[0];
    const float* s_x2h_w = (const float*)d_in[1];
    const float* s_x2h_b = (const float*)d_in[2];
    const float* s_h2h_w = (const float*)d_in[3];
    const float* s_h2h_b = (const float*)d_in[4];
    const float* p_x2h_w = (const float*)d_in[5];
    const float* p_x2h_b = (const float*)d_in[6];
    const float* p_h2h_w = (const float*)d_in[7];
    const float* p_h2h_b = (const float*)d_in[8];
    const float* p_fc_w  = (const float*)d_in[9];
    const float* p_fc_b  = (const float*)d_in[10];
    const float* fs_w    = (const float*)d_in[11];
    const float* fs_b    = (const float*)d_in[12];

    char* ws = (char*)d_ws;
    size_t off = 0;
    auto alloc = [&](size_t bytes) { void* p = ws + off; off += (bytes + 255) & ~(size_t)255; return p; };
    u16*   wS   = (u16*)  alloc((size_t)G4 * 1152 * 2);
    u16*   wP   = (u16*)  alloc((size_t)G4 * 1152 * 2);
    u16*   fswb = (u16*)  alloc((size_t)8 * 32 * 512 * 2);
    u16*   pfcb = (u16*)  alloc((size_t)16 * 32 * 512 * 2);
    float* bS   = (float*)alloc((size_t)G4 * 4);
    float* bP   = (float*)alloc((size_t)G4 * 4);
    u16*   acts = (u16*)  alloc((size_t)2 * ACTE * 2);
    u16*   actp = (u16*)  alloc((size_t)2 * ACTE * 2);
    float* mbuf = (float*)alloc((size_t)BB * DD * 4);
    u32*   bars = (u32*)  alloc(2048);

    k_wgates<<<dim3(2304), 256, 0, stream>>>(s_x2h_w, s_h2h_w, wS);
    k_wgates<<<dim3(2304), 256, 0, stream>>>(p_x2h_w, p_h2h_w, wP);
    k_wplain<<<dim3(64),  256, 0, stream>>>(fs_w, fswb, 8, 1024);
    k_wplain<<<dim3(128), 256, 0, stream>>>(p_fc_w, pfcb, 16, 1024);
    k_bias2<<<dim3(16), 256, 0, stream>>>(s_x2h_b, s_h2h_b, bS);
    k_bias2<<<dim3(16), 256, 0, stream>>>(p_x2h_b, p_h2h_b, bP);
    k_zero<<<dim3(2304), 256, 0, stream>>>(acts, actp, bars);
    k_fillx<<<dim3(128), 256, 0, stream>>>(x, acts);

    SArgs sa;
    sa.acts = acts; sa.actp = actp;
    sa.wS = wS; sa.wP = wP; sa.fswb = fswb; sa.pfcb = pfcb;
    sa.bS = bS; sa.bP = bP; sa.fsb = fs_b; sa.pfb = p_fc_b; sa.x = x;
    sa.mbuf = mbuf; sa.out = (float*)d_out; sa.bars = bars;

    void* kargs[] = { &sa };
    hipError_t e = hipLaunchCooperativeKernel((const void*)k_scan, dim3(256), dim3(512),
                                              kargs, 0, stream);
    if (e != hipSuccess) {
        k_scan<<<dim3(256), dim3(512), 0, stream>>>(sa);
    }
}

// Round 6
// 5062.862 us; speedup vs baseline: 2.8019x; 1.0750x over previous
//
#include <hip/hip_runtime.h>
#include <math.h>

#define BB 256
#define TT 128
#define DD 128
#define HH 1024
#define G4 4096
#define TOUT 127
#define OSZ (BB * TOUT * DD)
#define NKB 36                  // (128+1024)/32 K-blocks of the gates GEMM
#define ACTE (16 * NKB * 512)   // u16 elems of one activation frag-blob: 294912

typedef __bf16 bf16x8 __attribute__((ext_vector_type(8)));
typedef float f32x4 __attribute__((ext_vector_type(4)));
typedef unsigned short u16;
typedef unsigned int u32;
typedef unsigned long long u64;

#define MFMA16 __builtin_amdgcn_mfma_f32_16x16x32_bf16

__device__ inline u16 f2bf(float f) {
    union { float f; u32 u; } v; v.f = f;
    u32 r = v.u + 0x7FFFu + ((v.u >> 16) & 1u);
    return (u16)(r >> 16);
}
__device__ inline float fsig(float x)  { return __fdividef(1.0f, 1.0f + __expf(-x)); }
__device__ inline float ftanh(float x) { return __fdividef(2.0f, 1.0f + __expf(-2.0f * x)) - 1.0f; }

// Coherent (agent-scope, relaxed) activation access: bypasses stale L1/L2,
// served at the L3 coherence point. NO cache-maintenance fences anywhere.
__device__ __forceinline__ bf16x8 ld_act(const u16* p) {
    union { u64 q[2]; bf16x8 v; } u;
    u.q[0] = __hip_atomic_load((u64*)p,     __ATOMIC_RELAXED, __HIP_MEMORY_SCOPE_AGENT);
    u.q[1] = __hip_atomic_load((u64*)p + 1, __ATOMIC_RELAXED, __HIP_MEMORY_SCOPE_AGENT);
    return u.v;
}
__device__ __forceinline__ void st_u32(u16* p, u32 v) {
    __hip_atomic_store((u32*)p, v, __ATOMIC_RELAXED, __HIP_MEMORY_SCOPE_AGENT);
}

// Grid barrier, no cache-maintenance: drain write-through stores, relaxed add,
// relaxed polls with sleep backoff. 32 padded counters, 8 arrivals each.
__device__ __forceinline__ void gbar(u32* bars, u32 gen) {
    asm volatile("s_waitcnt vmcnt(0)" ::: "memory");
    __syncthreads();
    if (threadIdx.x == 0)
        __hip_atomic_fetch_add(&bars[(blockIdx.x & 31) << 4], 1u,
                               __ATOMIC_RELAXED, __HIP_MEMORY_SCOPE_AGENT);
    if (threadIdx.x < 32) {
        while (__hip_atomic_load(&bars[threadIdx.x << 4],
                                 __ATOMIC_RELAXED, __HIP_MEMORY_SCOPE_AGENT) < gen * 8u)
            __builtin_amdgcn_s_sleep(4);
    }
    __syncthreads();
}

struct SArgs {
    u16 *acts, *actp;                       // 2 x ACTE each (double-buffered blobs)
    const u16 *wS, *wP, *fswb, *pfcb;       // frag-ordered weight blobs (L2-resident)
    const float *bS, *bP, *fsb, *pfb, *x;
    float* mbuf;                            // mask scratch (coherent path)
    float* out;
    u32* bars;
};

// Gates GEMM 256x4096 (K=1152) + fused LSTM cell. Tile 32m x 128n per block;
// grid: bm = bid>>5 (8 m-groups), bn = bid&31 (32 n-slices; bid%8 == bn%8 so
// blocks sharing a B-slice share an XCD -> B L2-resident).
// Waves: kg(2, K-split) x wv(4, n-quarter). A panel (32x1152 bf16) staged once
// into LDS via coherent loads; B register-direct from L2 with double-buffered
// prefetch. 2-way kg LDS reduce; epilogue + c-update + h-blob write on kg==0.
__device__ __forceinline__ void lstm_phase(
    const u16* __restrict__ act, const u16* __restrict__ wb,
    const float* __restrict__ bias, float* __restrict__ cst /*LDS [32][32]*/,
    u16* __restrict__ hact, float* __restrict__ red /*LDS 16KB*/,
    u64* __restrict__ a_lds /*LDS 73728B*/,
    int bid, int w, int lane)
{
    const int tid = threadIdx.x;
    const int bm = bid >> 5, bn = bid & 31;
    const int kg = w >> 2, wv = w & 3;

    // ---- stage A panel: blob rows mblk {2bm, 2bm+1}, all 36 kblks ----
    {
        const u64* src = (const u64*)(act + (size_t)bm * 2 * NKB * 512);
#pragma unroll
        for (int u = 0; u < 18; ++u) {
            int idx = tid + u * 512;  // 9216 u64 total
            a_lds[idx] = __hip_atomic_load(&src[idx], __ATOMIC_RELAXED,
                                           __HIP_MEMORY_SCOPE_AGENT);
        }
    }
    __syncthreads();

    const u16* ab = (const u16*)a_lds;
    const u16* a0p = ab + (((0 * NKB) + kg * 18) * 64 + lane) * 8;
    const u16* a1p = ab + (((1 * NKB) + kg * 18) * 64 + lane) * 8;
    const u16* b0p = wb + (((size_t)(bn * 8 + wv * 2 + 0) * NKB + kg * 18) * 64 + lane) * 8;
    const u16* b1p = wb + (((size_t)(bn * 8 + wv * 2 + 1) * NKB + kg * 18) * 64 + lane) * 8;

    f32x4 acc[2][2] = {};
    bf16x8 bc0 = *(const bf16x8*)(b0p);
    bf16x8 bc1 = *(const bf16x8*)(b1p);
#pragma unroll 6
    for (int it = 0; it < 18; ++it) {
        bf16x8 bn0, bn1;
        if (it < 17) {
            bn0 = *(const bf16x8*)(b0p + (it + 1) * 512);
            bn1 = *(const bf16x8*)(b1p + (it + 1) * 512);
        }
        bf16x8 a0 = *(const bf16x8*)(a0p + it * 512);
        bf16x8 a1 = *(const bf16x8*)(a1p + it * 512);
        acc[0][0] = MFMA16(a0, bc0, acc[0][0], 0, 0, 0);
        acc[0][1] = MFMA16(a0, bc1, acc[0][1], 0, 0, 0);
        acc[1][0] = MFMA16(a1, bc0, acc[1][0], 0, 0, 0);
        acc[1][1] = MFMA16(a1, bc1, acc[1][1], 0, 0, 0);
        if (it < 17) { bc0 = bn0; bc1 = bn1; }
    }

    if (kg == 1) {
#pragma unroll
        for (int mi = 0; mi < 2; ++mi)
#pragma unroll
        for (int bi = 0; bi < 2; ++bi)
            *(f32x4*)&red[(((((wv << 1) | mi) << 1) | bi) << 8) + (lane << 2)] = acc[mi][bi];
    }
    __syncthreads();

    if (kg == 0) {
        const int col = lane & 15, row4 = (lane >> 4) << 2, g0 = lane & 3;
#pragma unroll
        for (int mi = 0; mi < 2; ++mi)
#pragma unroll
        for (int bi = 0; bi < 2; ++bi) {
            f32x4 s1 = *(const f32x4*)&red[(((((wv << 1) | mi) << 1) | bi) << 8) + (lane << 2)];
            const int n = bn * 128 + (wv * 2 + bi) * 16 + col;
            const float bv = bias[n];
#pragma unroll
            for (int rr = 0; rr < 4; ++rr) {
                float v = acc[mi][bi][rr] + s1[rr] + bv;
                float v1 = __shfl_xor(v, 1);
                float v2 = __shfl_xor(v, 2);
                float v3 = __shfl_xor(v, 3);
                const int m = bm * 32 + mi * 16 + row4 + rr;
                const int j = n >> 2;
                u32 hbits = 0;
                if (g0 == 0) {  // lane holds gate i; v1=f, v2=g, v3=o
                    const int ml = mi * 16 + row4 + rr;
                    const int jl = j - bn * 32;
                    float cp = cst[ml * 32 + jl];
                    float cy = cp * fsig(v1) + fsig(v) * ftanh(v2);
                    float hy = fsig(v3) * ftanh(cy);
                    cst[ml * 32 + jl] = cy;
                    hbits = (u32)f2bf(hy);
                }
                // pair (j even, j odd) from lanes l, l^4 -> one 4B coherent store
                u32 pv = hbits | (((u32)__shfl_xor((int)hbits, 4)) << 16);
                if ((lane & 7) == 0)
                    st_u32(&hact[(((size_t)(m >> 4) * NKB + (4 + (j >> 5))) * 64 +
                                  ((m & 15) + (((j >> 3) & 3) << 4))) * 8 + (j & 7)], pv);
            }
        }
    }
}

__global__ __launch_bounds__(512, 2) void k_scan(SArgs A)
{
    __shared__ __align__(16) u64 a_lds[9216];   // 72 KB staged A panel
    __shared__ __align__(16) float red[4096];   // 16 KB reduce scratch
    __shared__ float cst[2][32][32];            // 8 KB persistent c state (s,p)

    const int bid = blockIdx.x, tid = threadIdx.x;
    const int w = tid >> 6, lane = tid & 63;

    for (int i = tid; i < 2 * 32 * 32; i += 512) ((float*)cst)[i] = 0.f;

    float* o_mask = A.out;
    float* o_x0   = A.out + 1 * (size_t)OSZ;
    float* o_x1   = A.out + 2 * (size_t)OSZ;
    float* o_reg  = A.out + 3 * (size_t)OSZ;
    float* o_mu   = A.out + 4 * (size_t)OSZ;
    float* o_prob = A.out + 5 * (size_t)OSZ;
    float* o_z    = A.out + 6 * (size_t)OSZ;

    u32 gen = 0;

    for (int t = 0; t < TOUT; ++t) {
        const u16* s_cur = A.acts + (size_t)(t & 1) * ACTE;
        u16*       s_nxt = A.acts + (size_t)((t + 1) & 1) * ACTE;
        u16*       p_cur = A.actp + (size_t)(t & 1) * ACTE;
        u16*       p_nxt = A.actp + (size_t)((t + 1) & 1) * ACTE;

        // ---- phase S ----
        lstm_phase(s_cur, A.wS, A.bS, &cst[0][0][0], s_nxt, red, a_lds, bid, w, lane);
        gbar(A.bars, ++gen);

        // ---- phase M: mu GEMM (256x128,K=1024), 128 blocks, 8-wave K-split ----
        if (bid < 128) {
            const int bm = bid >> 3, bn = bid & 7;
            f32x4 acc = {};
#pragma unroll
            for (int i = 0; i < 4; ++i) {
                const int kb = (w << 2) + i;
                bf16x8 av = ld_act(s_nxt + (((size_t)bm * NKB + 4 + kb) * 64 + lane) * 8);
                bf16x8 bv = *(const bf16x8*)(A.fswb + (((size_t)bn * 32 + kb) * 64 + lane) * 8);
                acc = MFMA16(av, bv, acc, 0, 0, 0);
            }
            *(f32x4*)&red[(w * 64 + lane) << 2] = acc;
            __syncthreads();
            if (tid < 256) {
                const int m16 = tid >> 4, d16 = tid & 15;
                const int rl = ((m16 >> 2) << 4) | d16, rr = m16 & 3;
                float v = 0.f;
#pragma unroll
                for (int ww = 0; ww < 8; ++ww) v += red[((ww * 64 + rl) << 2) + rr];
                const int m = (bm << 4) + m16, d = (bn << 4) + d16;
                float mu = v + A.fsb[d];
                float mask = fminf(fmaxf(mu + 0.5f, 0.f), 1.f);
                float reg = 0.5f * (1.0f + erff((mu + 0.5f) * 1.41421356237f));
                const size_t o = (size_t)m * (TOUT * DD) + (size_t)t * DD + d;
                o_mask[o] = mask; o_reg[o] = reg; o_mu[o] = mu; o_prob[o] = reg; o_z[o] = mu;
                __hip_atomic_store(&A.mbuf[m * DD + d], mask,
                                   __ATOMIC_RELAXED, __HIP_MEMORY_SCOPE_AGENT);
                float xv = A.x[(size_t)m * (TT * DD) + (size_t)(t + 1) * DD + d];
                u32 xb = (u32)f2bf(mask * xv);
                u32 pv = xb | (((u32)__shfl_xor((int)xb, 1)) << 16);
                if ((d16 & 1) == 0)
                    st_u32(&p_cur[(((size_t)(m >> 4) * NKB + (d >> 5)) * 64 +
                                   ((m & 15) + (((d >> 3) & 3) << 4))) * 8 + (d & 7)], pv);
            }
        }
        gbar(A.bars, ++gen);

        // ---- phase P ----
        lstm_phase(p_cur, A.wP, A.bP, &cst[1][0][0], p_nxt, red, a_lds, bid, w, lane);
        gbar(A.bars, ++gen);

        // ---- phase F: fc GEMM (256x256,K=1024), 256 blocks, 8-wave K-split ----
        {
            const int bm = bid >> 4, bn = bid & 15;
            f32x4 acc = {};
#pragma unroll
            for (int i = 0; i < 4; ++i) {
                const int kb = (w << 2) + i;
                bf16x8 av = ld_act(p_nxt + (((size_t)bm * NKB + 4 + kb) * 64 + lane) * 8);
                bf16x8 bv = *(const bf16x8*)(A.pfcb + (((size_t)bn * 32 + kb) * 64 + lane) * 8);
                acc = MFMA16(av, bv, acc, 0, 0, 0);
            }
            *(f32x4*)&red[(w * 64 + lane) << 2] = acc;
            __syncthreads();
            if (tid < 256) {
                const int m16 = tid >> 4, d16 = tid & 15;
                const int rl = ((m16 >> 2) << 4) | d16, rr = m16 & 3;
                float v = 0.f;
#pragma unroll
                for (int ww = 0; ww < 8; ++ww) v += red[((ww * 64 + rl) << 2) + rr];
                const int m = (bm << 4) + m16, n = (bn << 4) + d16;
                v += A.pfb[n];
                const size_t ob = (size_t)m * (TOUT * DD) + (size_t)t * DD;
                if (bn < 8) {  // n < DD (block-uniform)
                    o_x0[ob + n] = v;
                    float mk = __hip_atomic_load(&A.mbuf[m * DD + n],
                                                 __ATOMIC_RELAXED, __HIP_MEMORY_SCOPE_AGENT);
                    float xv = A.x[(size_t)m * (TT * DD) + (size_t)(t + 1) * DD + n];
                    u32 ib = (u32)f2bf(mk * xv + (1.f - mk) * v);
                    u32 pv = ib | (((u32)__shfl_xor((int)ib, 1)) << 16);
                    if ((d16 & 1) == 0)
                        st_u32(&s_nxt[(((size_t)(m >> 4) * NKB + (n >> 5)) * 64 +
                                       ((m & 15) + (((n >> 3) & 3) << 4))) * 8 + (n & 7)], pv);
                } else {
                    o_x1[ob + (n - DD)] = v;
                }
            }
        }
        gbar(A.bars, ++gen);
    }
}

// ---------------- setup kernels (once per call) ----------------

__global__ void k_wgates(const float* __restrict__ wx, const float* __restrict__ wh,
                         u16* __restrict__ blob) {
    int i = blockIdx.x * 256 + threadIdx.x;
    if (i >= 256 * NKB * 64) return;
    int lane = i & 63, cblk = (i >> 6) % NKB, rblk = (i >> 6) / NKB;
    int n = (rblk << 4) | (lane & 15);
    int c = (cblk << 5) + ((lane >> 4) << 3);
    int orow = ((n & 3) << 10) | (n >> 2);
    const float* s = (cblk < 4) ? (wx + (size_t)orow * DD + c)
                                : (wh + (size_t)orow * HH + (c - 128));
    u16* d = blob + (size_t)i * 8;
#pragma unroll
    for (int k = 0; k < 8; ++k) d[k] = f2bf(s[k]);
}

__global__ void k_wplain(const float* __restrict__ wsrc, u16* __restrict__ blob,
                         int nblk, int K) {
    int CB = K >> 5;
    int i = blockIdx.x * 256 + threadIdx.x;
    if (i >= nblk * CB * 64) return;
    int lane = i & 63, cblk = (i >> 6) % CB, rblk = (i >> 6) / CB;
    int r = (rblk << 4) | (lane & 15);
    int c = (cblk << 5) + ((lane >> 4) << 3);
    const float* s = wsrc + (size_t)r * K + c;
    u16* d = blob + (size_t)i * 8;
#pragma unroll
    for (int k = 0; k < 8; ++k) d[k] = f2bf(s[k]);
}

__global__ void k_bias2(const float* __restrict__ bx, const float* __restrict__ bh,
                        float* __restrict__ dst) {
    int r = blockIdx.x * 256 + threadIdx.x;
    if (r < G4) {
        int o = ((r & 3) << 10) | (r >> 2);
        dst[r] = bx[o] + bh[o];
    }
}

__global__ void k_zero(u16* acts, u16* actp, u32* bars) {
    size_t i = (size_t)blockIdx.x * 256 + threadIdx.x;
    if (i < 2 * (size_t)ACTE) { acts[i] = 0; actp[i] = 0; }
    if (i < 512) bars[i] = 0;
}

__global__ void k_fillx(const float* __restrict__ x, u16* __restrict__ acts) {
    int i = blockIdx.x * 256 + threadIdx.x;
    if (i >= BB * DD) return;
    int m = i >> 7, d = i & 127;
    acts[(((size_t)(m >> 4) * NKB + (d >> 5)) * 64 +
          ((m & 15) + (((d >> 3) & 3) << 4))) * 8 + (d & 7)] =
        f2bf(x[(size_t)m * (TT * DD) + d]);
}

extern "C" void kernel_launch(void* const* d_in, const int* in_sizes, int n_in,
                              void* d_out, int out_size, void* d_ws, size_t ws_size,
                              hipStream_t stream) {
    const float* x       = (const float*)d_in[0];
    const float* s_x2h_w = (const float*)d_in[1];
    const float* s_x2h_b = (const float*)d_in[2];
    const float* s_h2h_w = (const float*)d_in[3];
    const float* s_h2h_b = (const float*)d_in[4];
    const float* p_x2h_w = (const float*)d_in[5];
    const float* p_x2h_b = (const float*)d_in[6];
    const float* p_h2h_w = (const float*)d_in[7];
    const float* p_h2h_b = (const float*)d_in[8];
    const float* p_fc_w  = (const float*)d_in[9];
    const float* p_fc_b  = (const float*)d_in[10];
    const float* fs_w    = (const float*)d_in[11];
    const float* fs_b    = (const float*)d_in[12];

    char* ws = (char*)d_ws;
    size_t off = 0;
    auto alloc = [&](size_t bytes) { void* p = ws + off; off += (bytes + 255) & ~(size_t)255; return p; };
    u16*   wS   = (u16*)  alloc((size_t)G4 * 1152 * 2);
    u16*   wP   = (u16*)  alloc((size_t)G4 * 1152 * 2);
    u16*   fswb = (u16*)  alloc((size_t)8 * 32 * 512 * 2);
    u16*   pfcb = (u16*)  alloc((size_t)16 * 32 * 512 * 2);
    float* bS   = (float*)alloc((size_t)G4 * 4);
    float* bP   = (float*)alloc((size_t)G4 * 4);
    u16*   acts = (u16*)  alloc((size_t)2 * ACTE * 2);
    u16*   actp = (u16*)  alloc((size_t)2 * ACTE * 2);
    float* mbuf = (float*)alloc((size_t)BB * DD * 4);
    u32*   bars = (u32*)  alloc(2048);

    k_wgates<<<dim3(2304), 256, 0, stream>>>(s_x2h_w, s_h2h_w, wS);
    k_wgates<<<dim3(2304), 256, 0, stream>>>(p_x2h_w, p_h2h_w, wP);
    k_wplain<<<dim3(64),  256, 0, stream>>>(fs_w, fswb, 8, 1024);
    k_wplain<<<dim3(128), 256, 0, stream>>>(p_fc_w, pfcb, 16, 1024);
    k_bias2<<<dim3(16), 256, 0, stream>>>(s_x2h_b, s_h2h_b, bS);
    k_bias2<<<dim3(16), 256, 0, stream>>>(p_x2h_b, p_h2h_b, bP);
    k_zero<<<dim3(2304), 256, 0, stream>>>(acts, actp, bars);
    k_fillx<<<dim3(128), 256, 0, stream>>>(x, acts);

    SArgs sa;
    sa.acts = acts; sa.actp = actp;
    sa.wS = wS; sa.wP = wP; sa.fswb = fswb; sa.pfcb = pfcb;
    sa.bS = bS; sa.bP = bP; sa.fsb = fs_b; sa.pfb = p_fc_b; sa.x = x;
    sa.mbuf = mbuf; sa.out = (float*)d_out; sa.bars = bars;

    void* kargs[] = { &sa };
    hipError_t e = hipLaunchCooperativeKernel((const void*)k_scan, dim3(256), dim3(512),
                                              kargs, 0, stream);
    if (e != hipSuccess) {
        k_scan<<<dim3(256), dim3(512), 0, stream>>>(sa);
    }
}